// Round 8
// baseline (53.354 us; speedup 1.0000x reference)
//
#include <hip/hip_runtime.h>
#include <math.h>

// Problem constants (from reference)
constexpr int kC   = 3;
constexpr int kTIn = 2048;
constexpr int kR   = 64;
constexpr int kTB  = 128;
constexpr float kAlpha = 10.0f;
constexpr float kLog2e = 1.44269504088896f;

constexpr int kK   = 4;              // samples per block
constexpr int kF4  = kC * kTIn / 4;  // 1536 float4 per sample

#ifndef __has_builtin
#define __has_builtin(x) 0
#endif

static __device__ __forceinline__ float fast_rcp(float x) {
#if __has_builtin(__builtin_amdgcn_rcpf)
    return __builtin_amdgcn_rcpf(x);
#else
    return 1.0f / x;
#endif
}

static __device__ __forceinline__ float fast_exp2(float x) {
#if __has_builtin(__builtin_amdgcn_exp2f)
    return __builtin_amdgcn_exp2f(x);
#else
    return __builtin_exp2f(x);
#endif
}

static __device__ __forceinline__ void sched_pin() {
#if __has_builtin(__builtin_amdgcn_sched_barrier)
    __builtin_amdgcn_sched_barrier(0);
#endif
}

// Raw barrier: does NOT drain vmcnt (unlike __syncthreads) -> in-flight
// global loads survive. Producer side must lgkmcnt(0) before it.
static __device__ __forceinline__ void bar_publish() {
    asm volatile("s_waitcnt lgkmcnt(0)" ::: "memory");
    __builtin_amdgcn_s_barrier();
    asm volatile("" ::: "memory");
}
static __device__ __forceinline__ void bar_wait() {
    asm volatile("" ::: "memory");
    __builtin_amdgcn_s_barrier();
    asm volatile("" ::: "memory");
}

// ---------------------------------------------------------------------------
// Per-resonator transcendental params, once (libm accuracy).
// ws: [4][kR] = freq, decay, thr, thrE (= ALPHA*log2e*thr)
// ---------------------------------------------------------------------------
__global__ void param_kernel(const float* __restrict__ freq_raw,
                             const float* __restrict__ q_raw,
                             const float* __restrict__ thr_raw,
                             float* __restrict__ pp)
{
    const int r = threadIdx.x;
    if (r >= kR) return;
    const float freq  = 0.03f + 0.17f / (1.0f + expf(-freq_raw[r]));
    const float qf    = 1.5f + log1pf(expf(q_raw[r]));
    const float decay = expf(-1.0f / qf);
    const float thr   = 0.35f + 0.75f / (1.0f + expf(-thr_raw[r]));
    pp[0 * kR + r] = freq;
    pp[1 * kR + r] = decay;
    pp[2 * kR + r] = thr;
    pp[3 * kR + r] = thr * (kAlpha * kLog2e);
}

// ---------------------------------------------------------------------------
// Wave-specialized producer/consumer with cross-barrier prefetch.
// 4 waves/block, K=4 samples, 2048 blocks fully resident (32 waves/CU).
//   helpers (3): consume R (loads issued one barrier ago, fully drained by
//                now) -> pool into sp[buf] + red[buf]; issue next sample's
//                loads; lgkmcnt(0); raw s_barrier (vmcnt survives!).
//   scanner (1, = blockIdx&3): scan sp[cur] between barriers, setprio(1).
// Memory queue never empties -> no per-iteration refill bubble.
// ---------------------------------------------------------------------------
__global__ __launch_bounds__(256, 8)
void fused_encoder_kernel(const float* __restrict__ traces,
                          const float* __restrict__ drive_w,
                          const float* __restrict__ drive_b,
                          const float* __restrict__ pp,
                          float* __restrict__ out)
{
    __shared__ float sp[2][kTB * 4];   // [buf][t*4+c], 4 KB
    __shared__ float red[2][3];        // per-helper-wave maxes

    const int tid  = threadIdx.x;
    const int wave = tid >> 6;
    const int lane = tid & 63;
    const int scanWave = blockIdx.x & 3;
    const long long base = (long long)blockIdx.x * kK;
    const float4* tr4 = reinterpret_cast<const float4*>(traces);

    if (wave != scanWave) {
        // ================= helper: load + pool + max =================
        const int h = wave - (wave > scanWave ? 1 : 0);   // 0..2

        float4 R[8];                                       // 32 VGPR in flight
        auto issue = [&](long long b) {
            const float4* src = tr4 + b * kF4 + (h * 8) * 64 + lane;
            #pragma unroll
            for (int j = 0; j < 8; ++j) R[j] = src[j * 64];
        };
        auto consume = [&](int buf) {
            float mloc = 0.0f;
            #pragma unroll
            for (int j = 0; j < 8; ++j) {
                float4 v = R[j];
                float s = (v.x + v.y) + (v.z + v.w);
                s += __shfl_xor(s, 1, 64);
                s += __shfl_xor(s, 2, 64);                // window sum in quad
                mloc = fmaxf(mloc, fabsf(s));
                if ((lane & 3) == 0) {
                    int w = (h * 8 + j) * 16 + (lane >> 2);   // w = c*128 + t
                    sp[buf][(w & 127) * 4 + (w >> 7)] = s;
                }
            }
            #pragma unroll
            for (int off = 4; off <= 32; off <<= 1)       // quads already uniform
                mloc = fmaxf(mloc, __shfl_xor(mloc, off, 64));
            if (lane == 0) red[buf][h] = mloc;
        };

        issue(base + 0);
        consume(0);                       // prologue (unavoidable cold stall)
        issue(base + 1);
        sched_pin();
        bar_publish();                    // BAR 0: publish sp[0]; loads in flight
        for (int k = 0; k < kK - 1; ++k) {
            consume((k + 1) & 1);         // loads had a full iteration to land
            if (k + 2 < kK) issue(base + k + 2);
            sched_pin();
            bar_publish();                // BAR k+1: publish sp[k+1]
        }
    } else {
        // ================= scanner: params + 128-step scan =================
        const int r = lane;
        const float w0   = drive_w[r * kC + 0];
        const float w1   = drive_w[r * kC + 1];
        const float w2   = drive_w[r * kC + 2];
        const float bias = drive_b[r];
        const float freq  = pp[0 * kR + r];
        const float decay = pp[1 * kR + r];
        const float thr   = pp[2 * kR + r];
        const float thrE  = pp[3 * kR + r];
        const float expScale = kAlpha * kLog2e;

        bar_wait();                       // BAR 0
        for (int k = 0; k < kK; ++k) {
            const int cur = k & 1;
            const float mm = fmaxf(fmaxf(red[cur][0], red[cur][1]), red[cur][2]);
            const float inv = fast_rcp(fmaxf(mm * (1.0f / 16.0f), 1.0f)) * (1.0f / 16.0f);
            const float v0 = w0 * inv, v1 = w1 * inv, v2 = w2 * inv;
            const float4* pt = reinterpret_cast<const float4*>(sp[cur]);

            __builtin_amdgcn_s_setprio(1);
            float state = 0.0f, vel = 0.0f, acc = 0.0f;
            #pragma unroll 8
            for (int t = 0; t < kTB; ++t) {
                float4 p = pt[t];                     // broadcast ds_read_b128
                float cur_ = fmaf(p.x, v0, bias);
                cur_ = fmaf(p.y, v1, cur_);
                cur_ = fmaf(p.z, v2, cur_);
                vel = fmaf(decay, vel, cur_);
                vel = fmaf(-freq, state, vel);
                state = fmaf(freq, vel, state);
                float e = fast_exp2(fmaf(-expScale, state, thrE));
                float spike = fast_rcp(1.0f + e);
                state = fmaf(-spike, thr, state);
                acc += spike;
            }
            __builtin_amdgcn_s_setprio(0);

            out[(base + k) * kR + r] = acc * (1.0f / kTB);
            if (k < kK - 1) bar_wait();   // BAR k+1
        }
    }
}

extern "C" void kernel_launch(void* const* d_in, const int* in_sizes, int n_in,
                              void* d_out, int out_size, void* d_ws, size_t ws_size,
                              hipStream_t stream)
{
    const float* traces   = (const float*)d_in[0];
    const float* drive_w  = (const float*)d_in[1];
    const float* drive_b  = (const float*)d_in[2];
    const float* freq_raw = (const float*)d_in[3];
    const float* q_raw    = (const float*)d_in[4];
    const float* thr_raw  = (const float*)d_in[5];
    float* out = (float*)d_out;
    float* pp  = (float*)d_ws;

    const int totalB = in_sizes[0] / (kC * kTIn);   // 8192
    const int grid = totalB / kK;                   // 2048 blocks, fully resident

    param_kernel<<<1, 64, 0, stream>>>(freq_raw, q_raw, thr_raw, pp);
    fused_encoder_kernel<<<grid, 256, 0, stream>>>(traces, drive_w, drive_b, pp, out);
}

// Round 9
// 49.612 us; speedup vs baseline: 1.0754x; 1.0754x over previous
//
#include <hip/hip_runtime.h>
#include <math.h>

// Problem constants (from reference)
constexpr int kC   = 3;
constexpr int kTIn = 2048;
constexpr int kR   = 64;
constexpr int kTB  = 128;
constexpr float kAlpha = 10.0f;
constexpr float kLog2e = 1.44269504088896f;

constexpr int kK   = 4;              // samples per block
constexpr int kF4  = kC * kTIn / 4;  // 1536 float4 per sample

#ifndef __has_builtin
#define __has_builtin(x) 0
#endif

static __device__ __forceinline__ float fast_rcp(float x) {
#if __has_builtin(__builtin_amdgcn_rcpf)
    return __builtin_amdgcn_rcpf(x);
#else
    return 1.0f / x;
#endif
}

static __device__ __forceinline__ float fast_exp2(float x) {
#if __has_builtin(__builtin_amdgcn_exp2f)
    return __builtin_amdgcn_exp2f(x);
#else
    return __builtin_exp2f(x);
#endif
}

static __device__ __forceinline__ void sched_pin() {
#if __has_builtin(__builtin_amdgcn_sched_barrier)
    __builtin_amdgcn_sched_barrier(0);
#endif
}

// Publish barrier: drain LDS writes only (lgkmcnt). Global loads stay in
// flight across it (unlike __syncthreads' vmcnt(0) drain).
static __device__ __forceinline__ void bar_publish() {
    asm volatile("s_waitcnt lgkmcnt(0)" ::: "memory");
    __builtin_amdgcn_s_barrier();
    asm volatile("" ::: "memory");
}
static __device__ __forceinline__ void bar_wait() {
    asm volatile("" ::: "memory");
    __builtin_amdgcn_s_barrier();
    asm volatile("" ::: "memory");
}

// ---------------------------------------------------------------------------
// Wave-specialized producer/consumer, K=4 samples/block, 2048 blocks fully
// resident (32 waves/CU).
//   helpers (3 waves): half-batch ping-pong -- consume H0(k+1) / issue
//     H0(k+2) / consume H1(k+1) / issue H1(k+2) -> counted vmcnt waits,
//     >=4 loads in flight at ALL times (queue never empties).
//   scanner (1 wave, = blockIdx&3): computes resonator params in the
//     prologue shadow, then scans sp[cur] between raw barriers.
// ---------------------------------------------------------------------------
__global__ __launch_bounds__(256, 8)
void fused_encoder_kernel(const float* __restrict__ traces,
                          const float* __restrict__ drive_w,
                          const float* __restrict__ drive_b,
                          const float* __restrict__ freq_raw,
                          const float* __restrict__ q_raw,
                          const float* __restrict__ thr_raw,
                          float* __restrict__ out)
{
    __shared__ float sp[2][kTB * 4];   // [buf][t*4+c], 4 KB
    __shared__ float red[2][3];        // per-helper-wave maxes

    const int tid  = threadIdx.x;
    const int wave = tid >> 6;
    const int lane = tid & 63;
    const int scanWave = blockIdx.x & 3;
    const long long base = (long long)blockIdx.x * kK;
    const float4* tr4 = reinterpret_cast<const float4*>(traces);

    if (wave != scanWave) {
        // ================= helper: load + pool + max =================
        const int h = wave - (wave > scanWave ? 1 : 0);   // 0..2
        const float4* src0 = tr4 + (h * 8) * 64 + lane;   // + b*kF4 + j*64

        float4 R[8];                                       // 32 VGPR staged
        float  mloc;

        auto issueHalf = [&](long long b, int half) {
            const float4* src = src0 + b * kF4 + half * 4 * 64;
            #pragma unroll
            for (int j = 0; j < 4; ++j) R[half * 4 + j] = src[j * 64];
        };
        auto consumeHalf = [&](int half, int buf) {
            #pragma unroll
            for (int j = 0; j < 4; ++j) {
                float4 v = R[half * 4 + j];
                float s = (v.x + v.y) + (v.z + v.w);
                s += __shfl_xor(s, 1, 64);
                s += __shfl_xor(s, 2, 64);                // window sum in quad
                mloc = fmaxf(mloc, fabsf(s));
                if ((lane & 3) == 0) {
                    int w = (h * 8 + half * 4 + j) * 16 + (lane >> 2); // c*128+t
                    sp[buf][(w & 127) * 4 + (w >> 7)] = s;
                }
            }
        };
        auto reduceMax = [&](int buf) {
            #pragma unroll
            for (int off = 4; off <= 32; off <<= 1)       // quads already uniform
                mloc = fmaxf(mloc, __shfl_xor(mloc, off, 64));
            if (lane == 0) red[buf][h] = mloc;
            mloc = 0.0f;
        };

        // prologue: sample 0 (cold), then sample 1's batch into flight
        mloc = 0.0f;
        issueHalf(base + 0, 0); issueHalf(base + 0, 1);
        consumeHalf(0, 0); consumeHalf(1, 0);
        reduceMax(0);
        issueHalf(base + 1, 0); issueHalf(base + 1, 1);
        sched_pin();
        bar_publish();                       // BAR0: sp[0] live; 8 loads in flight

        for (int k = 0; k + 1 < kK; ++k) {   // k = 0,1,2
            const int buf = (k + 1) & 1;
            const bool more = (k + 2 < kK);
            consumeHalf(0, buf);             // waits vmcnt(4): H1 still in flight
            if (more) { issueHalf(base + k + 2, 0); sched_pin(); }
            consumeHalf(1, buf);             // waits only on H1
            if (more) { issueHalf(base + k + 2, 1); sched_pin(); }
            reduceMax(buf);
            bar_publish();                   // BAR k+1
        }
    } else {
        // ================= scanner: params (hidden) + scans =================
        const int r = lane;
        const float w0   = drive_w[r * kC + 0];
        const float w1   = drive_w[r * kC + 1];
        const float w2   = drive_w[r * kC + 2];
        const float bias = drive_b[r];
        // transcendental params computed here, hidden under helpers' prologue
        const float freq  = 0.03f + 0.17f / (1.0f + expf(-freq_raw[r]));
        const float qf    = 1.5f + log1pf(expf(q_raw[r]));
        const float decay = expf(-1.0f / qf);
        const float thr   = 0.35f + 0.75f / (1.0f + expf(-thr_raw[r]));
        const float expScale = kAlpha * kLog2e;
        const float thrE  = thr * expScale;

        bar_wait();                          // BAR0
        for (int k = 0; k < kK; ++k) {
            const int cur = k & 1;
            const float mm = fmaxf(fmaxf(red[cur][0], red[cur][1]), red[cur][2]);
            const float inv = fast_rcp(fmaxf(mm * (1.0f / 16.0f), 1.0f)) * (1.0f / 16.0f);
            const float v0 = w0 * inv, v1 = w1 * inv, v2 = w2 * inv;
            const float4* pt = reinterpret_cast<const float4*>(sp[cur]);

            __builtin_amdgcn_s_setprio(1);
            float state = 0.0f, vel = 0.0f, acc = 0.0f;
            #pragma unroll 8
            for (int t = 0; t < kTB; ++t) {
                float4 p = pt[t];                     // broadcast ds_read_b128
                float cur_ = fmaf(p.x, v0, bias);
                cur_ = fmaf(p.y, v1, cur_);
                cur_ = fmaf(p.z, v2, cur_);
                vel = fmaf(decay, vel, cur_);
                vel = fmaf(-freq, state, vel);
                state = fmaf(freq, vel, state);
                float e = fast_exp2(fmaf(-expScale, state, thrE));
                float spike = fast_rcp(1.0f + e);
                state = fmaf(-spike, thr, state);
                acc += spike;
            }
            __builtin_amdgcn_s_setprio(0);

            out[(base + k) * kR + r] = acc * (1.0f / kTB);
            if (k + 1 < kK) bar_wait();       // BAR k+1
        }
    }
}

extern "C" void kernel_launch(void* const* d_in, const int* in_sizes, int n_in,
                              void* d_out, int out_size, void* d_ws, size_t ws_size,
                              hipStream_t stream)
{
    const float* traces   = (const float*)d_in[0];
    const float* drive_w  = (const float*)d_in[1];
    const float* drive_b  = (const float*)d_in[2];
    const float* freq_raw = (const float*)d_in[3];
    const float* q_raw    = (const float*)d_in[4];
    const float* thr_raw  = (const float*)d_in[5];
    float* out = (float*)d_out;

    const int totalB = in_sizes[0] / (kC * kTIn);   // 8192
    const int grid = totalB / kK;                   // 2048 blocks, fully resident

    fused_encoder_kernel<<<grid, 256, 0, stream>>>(traces, drive_w, drive_b,
                                                   freq_raw, q_raw, thr_raw, out);
}

// Round 10
// 40.124 us; speedup vs baseline: 1.3297x; 1.2365x over previous
//
#include <hip/hip_runtime.h>
#include <math.h>

// Problem constants (from reference)
constexpr int kC   = 3;
constexpr int kTIn = 2048;
constexpr int kR   = 64;
constexpr int kTB  = 128;
constexpr float kAlpha = 10.0f;
constexpr float kLog2e = 1.44269504088896f;

constexpr int kK   = 4;              // samples per block
constexpr int kF4  = kC * kTIn / 4;  // 1536 float4 per sample

#ifndef __has_builtin
#define __has_builtin(x) 0
#endif

static __device__ __forceinline__ float fast_rcp(float x) {
#if __has_builtin(__builtin_amdgcn_rcpf)
    return __builtin_amdgcn_rcpf(x);
#else
    return 1.0f / x;
#endif
}

static __device__ __forceinline__ float fast_exp2(float x) {
#if __has_builtin(__builtin_amdgcn_exp2f)
    return __builtin_amdgcn_exp2f(x);
#else
    return __builtin_exp2f(x);
#endif
}

// ---------------------------------------------------------------------------
// Wave-specialized producer/consumer block (exact round-7 structure: plain
// __syncthreads handoff, monolithic pool, NO hand-placed fences — the
// compiler's own progressive load/consume scheduling is what made R7 fast;
// R8/R9's explicit fences regressed it).
// 4 waves/block, K=4 samples, 2048 blocks fully resident (32 waves/CU).
//   helpers (3 waves): load+pool sample k+1 -> sp[nxt], wave-max -> red[nxt]
//   scanner (1 wave, = blockIdx&3 to spread across SIMDs): resonator params
//     computed in the prologue shadow (was a separate kernel), then scans.
// ---------------------------------------------------------------------------
__global__ __launch_bounds__(256, 8)
void fused_encoder_kernel(const float* __restrict__ traces,
                          const float* __restrict__ drive_w,
                          const float* __restrict__ drive_b,
                          const float* __restrict__ freq_raw,
                          const float* __restrict__ q_raw,
                          const float* __restrict__ thr_raw,
                          float* __restrict__ out)
{
    __shared__ float sp[2][kTB * 4];   // [buf][t*4+c], 4 KB
    __shared__ float red[2][3];        // per-helper-wave maxes

    const int tid  = threadIdx.x;
    const int wave = tid >> 6;
    const int lane = tid & 63;
    const int scanWave = blockIdx.x & 3;
    const long long base = (long long)blockIdx.x * kK;
    const float4* tr4 = reinterpret_cast<const float4*>(traces);

    if (wave != scanWave) {
        // ================= helper: load + pool + max =================
        const int h = wave - (wave > scanWave ? 1 : 0);   // 0..2

        auto pool = [&](long long b, int buf) {
            const float4* src = tr4 + b * kF4 + (h * 8) * 64 + lane;
            float mloc = 0.0f;
            #pragma unroll
            for (int j = 0; j < 8; ++j) {
                float4 v = src[j * 64];                   // coalesced 1 KB/inst
                float s = (v.x + v.y) + (v.z + v.w);
                s += __shfl_xor(s, 1, 64);
                s += __shfl_xor(s, 2, 64);                // window sum in quad
                mloc = fmaxf(mloc, fabsf(s));
                if ((lane & 3) == 0) {
                    int w = (h * 8 + j) * 16 + (lane >> 2);   // w = c*128 + t
                    sp[buf][(w & 127) * 4 + (w >> 7)] = s;
                }
            }
            #pragma unroll
            for (int off = 4; off <= 32; off <<= 1)       // quads already uniform
                mloc = fmaxf(mloc, __shfl_xor(mloc, off, 64));
            if (lane == 0) red[buf][h] = mloc;
        };

        pool(base, 0);                 // prologue: sample 0 -> buf 0
        __syncthreads();
        for (int k = 0; k < kK; ++k) {
            if (k + 1 < kK) pool(base + k + 1, (k + 1) & 1);
            __syncthreads();
        }
    } else {
        // ========== scanner: params (hidden under helpers' pool) + scans ====
        const int r = lane;
        const float w0   = drive_w[r * kC + 0];
        const float w1   = drive_w[r * kC + 1];
        const float w2   = drive_w[r * kC + 2];
        const float bias = drive_b[r];
        const float freq  = 0.03f + 0.17f / (1.0f + expf(-freq_raw[r]));
        const float qf    = 1.5f + log1pf(expf(q_raw[r]));
        const float decay = expf(-1.0f / qf);
        const float thr   = 0.35f + 0.75f / (1.0f + expf(-thr_raw[r]));
        const float expScale = kAlpha * kLog2e;
        const float thrE  = thr * expScale;

        __syncthreads();
        for (int k = 0; k < kK; ++k) {
            const int cur = k & 1;
            const float mm = fmaxf(fmaxf(red[cur][0], red[cur][1]), red[cur][2]);
            const float inv = fast_rcp(fmaxf(mm * (1.0f / 16.0f), 1.0f)) * (1.0f / 16.0f);
            const float v0 = w0 * inv, v1 = w1 * inv, v2 = w2 * inv;
            const float4* pt = reinterpret_cast<const float4*>(sp[cur]);

            __builtin_amdgcn_s_setprio(1);
            float state = 0.0f, vel = 0.0f, acc = 0.0f;
            #pragma unroll 8
            for (int t = 0; t < kTB; ++t) {
                float4 p = pt[t];                     // broadcast ds_read_b128
                float cur_ = fmaf(p.x, v0, bias);
                cur_ = fmaf(p.y, v1, cur_);
                cur_ = fmaf(p.z, v2, cur_);
                vel = fmaf(decay, vel, cur_);
                vel = fmaf(-freq, state, vel);
                state = fmaf(freq, vel, state);
                float e = fast_exp2(fmaf(-expScale, state, thrE));
                float spike = fast_rcp(1.0f + e);
                state = fmaf(-spike, thr, state);
                acc += spike;
            }
            __builtin_amdgcn_s_setprio(0);

            out[(base + k) * kR + r] = acc * (1.0f / kTB);
            __syncthreads();
        }
    }
}

extern "C" void kernel_launch(void* const* d_in, const int* in_sizes, int n_in,
                              void* d_out, int out_size, void* d_ws, size_t ws_size,
                              hipStream_t stream)
{
    const float* traces   = (const float*)d_in[0];
    const float* drive_w  = (const float*)d_in[1];
    const float* drive_b  = (const float*)d_in[2];
    const float* freq_raw = (const float*)d_in[3];
    const float* q_raw    = (const float*)d_in[4];
    const float* thr_raw  = (const float*)d_in[5];
    float* out = (float*)d_out;

    const int totalB = in_sizes[0] / (kC * kTIn);   // 8192
    const int grid = totalB / kK;                   // 2048 blocks, fully resident

    fused_encoder_kernel<<<grid, 256, 0, stream>>>(traces, drive_w, drive_b,
                                                   freq_raw, q_raw, thr_raw, out);
}